// Round 9
// baseline (229.674 us; speedup 1.0000x reference)
//
#include <hip/hip_runtime.h>
#include <math.h>

#define NORB 13
#define NORB2 (NORB * NORB)
#define NTHR 256
#define MAXE 256               // entries incident to one atom (mean ~32)
#define NBIN 128               // partner-atom bins (N <= 128)
#define MAXB 129               // distinct nonzero blocks (<= NBIN + diag)

typedef float fx2 __attribute__((ext_vector_type(2)));

// block id per orbital index for L_LIST=[0,0,1,1,2] -> sizes 1,1,3,3,5
__device__ __forceinline__ int blk_of(int p) {
    return p < 1 ? 0 : (p < 2 ? 1 : (p < 5 ? 2 : (p < 8 ? 3 : 4)));
}
__device__ __forceinline__ float bfac(int bp, int bq) {
    return bp < bq ? 1.0f : (bp == bq ? 0.5f : 0.0f);
}

// Sparse block writer: one WG per (k, a). CSR-bin the ~32 incident entries by
// partner atom b, precompute phases, then compute each DISTINCT nonzero 13x13
// block once and scatter it (~27 blocks x 1352 B = ~37 KB per WG, ~80 MB total).
// Runs after the stream-ordered hipMemsetAsync zero of the output.
__global__ void __launch_bounds__(NTHR)
k_sparse(const float* __restrict__ hopping,
         const float* __restrict__ onsite,
         const float* __restrict__ kpoints,
         const float* __restrict__ cell_shift,
         const int* __restrict__ edge_index,
         float* __restrict__ out,
         int N, int E, int K, int ld, int es) {
    int a = blockIdx.x % N;
    int k = blockIdx.x / N;
    int tid = threadIdx.x;

    __shared__ int   boff[NBIN + 1];   // counts -> CSR offsets
    __shared__ int   cur[NBIN];        // placement cursors
    __shared__ int   elist[MAXE];      // (e<<8) | (b<<1) | rev, sorted by b
    __shared__ float phc[MAXE];        // cos
    __shared__ float phs[MAXE];        // sin (sign-folded: conj for rev)
    __shared__ int   nzb[MAXB];        // b | i0<<7 | i1<<16
    __shared__ int   nnz;

    if (tid < NBIN) boff[tid] = 0;
    if (tid == 0) nnz = 0;
    __syncthreads();

    // count entries per partner atom b (edge list is 16 KB, L2-hot)
    for (int e = tid; e < E; e += NTHR) {
        int ie = edge_index[e], je = edge_index[E + e];
        if (ie == a) atomicAdd(&boff[je], 1);
        if (je == a) atomicAdd(&boff[ie], 1);
    }
    __syncthreads();

    // exclusive prefix over 128 bins: wave 0, 2 bins/lane, shfl scan
    if (tid < 64) {
        int v0 = boff[2 * tid], v1 = boff[2 * tid + 1];
        int s = v0 + v1, sc = s;
        #pragma unroll
        for (int d = 1; d < 64; d <<= 1) {
            int t = __shfl_up(sc, d);
            if (tid >= d) sc += t;
        }
        int excl = sc - s;
        boff[2 * tid] = excl;          cur[2 * tid] = excl;
        boff[2 * tid + 1] = excl + v0; cur[2 * tid + 1] = excl + v0;
        if (tid == 63) boff[NBIN] = sc;
    }
    __syncthreads();

    // place entries (counting sort by b)
    for (int e = tid; e < E; e += NTHR) {
        int ie = edge_index[e], je = edge_index[E + e];
        if (ie == a) {
            int pos = atomicAdd(&cur[je], 1);
            if (pos < MAXE) elist[pos] = (e << 8) | (je << 1);        // fwd
        }
        if (je == a) {
            int pos = atomicAdd(&cur[ie], 1);
            if (pos < MAXE) elist[pos] = (e << 8) | (ie << 1) | 1;    // rev
        }
    }
    __syncthreads();
    int nent = min(boff[NBIN], MAXE);

    // phases for this WG's single k
    float kx = kpoints[3 * k], ky = kpoints[3 * k + 1], kz = kpoints[3 * k + 2];
    for (int t = tid; t < nent; t += NTHR) {
        int ent = elist[t];
        int e = ent >> 8;
        float d = kx * cell_shift[3 * e] + ky * cell_shift[3 * e + 1]
                + kz * cell_shift[3 * e + 2];
        float s, c;
        __sincosf(-6.2831853071795864f * d, &s, &c);   // exp(-i*2pi*d) = c + i*s
        phc[t] = c;
        phs[t] = (ent & 1) ? -s : s;                   // conj for reverse
    }

    // enumerate nonzero blocks (bins with entries, plus the onsite diagonal)
    if (tid < NBIN) {
        int i0 = boff[tid];
        int i1 = boff[tid + 1]; if (i1 > MAXE) i1 = MAXE;
        if (i1 > i0 || tid == a) {
            int s = atomicAdd(&nnz, 1);
            nzb[s] = tid | (i0 << 7) | (i1 << 16);
        }
    }
    __syncthreads();
    int nb = nnz;

    const float* on = onsite + (size_t)a * NORB2;
    size_t rb = (size_t)(k * ld + a * NORB) * ld;      // complex units

    int tot = nb * NORB2;
    for (int idx = tid; idx < tot; idx += NTHR) {
        int blk = idx / NORB2;             // const-169 magic div
        int r   = idx - blk * NORB2;
        int p = r / NORB, q = r - p * NORB; // const-13 magic div
        int info = nzb[blk];
        int b  = info & 127;
        int i0 = (info >> 7) & 511, i1 = (info >> 16) & 511;
        int bp = blk_of(p), bq = blk_of(q);
        float fpq = bfac(bp, bq), fqp = bfac(bq, bp);
        float ax = 0.f, ay = 0.f;
        if (b == a)                         // hermitized onsite (real)
            ax = on[p * NORB + q] * fpq + on[q * NORB + p] * fqp;
        for (int it = i0; it < i1; ++it) {
            int ent = elist[it];
            const float* h = hopping + (size_t)(ent >> 8) * NORB2;
            float hv = (ent & 1) ? h[q * NORB + p] * fqp
                                 : h[p * NORB + q] * fpq;
            ax += phc[it] * hv;
            ay += phs[it] * hv;
        }
        size_t ci = rb + (size_t)p * ld + (size_t)b * NORB + q;
        if (es == 2) ((fx2*)out)[ci] = (fx2){ax, ay};
        else         out[ci] = ax;
    }
}

extern "C" void kernel_launch(void* const* d_in, const int* in_sizes, int n_in,
                              void* d_out, int out_size, void* d_ws, size_t ws_size,
                              hipStream_t stream) {
    const float* hopping    = (const float*)d_in[0];
    const float* onsite     = (const float*)d_in[1];
    const float* kpoints    = (const float*)d_in[2];
    const float* cell_shift = (const float*)d_in[3];
    const int*   edge_index = (const int*)d_in[4];
    float* out = (float*)d_out;

    int E = in_sizes[0] / NORB2;   // 2048
    int N = in_sizes[1] / NORB2;   // 128
    int K = in_sizes[2] / 3;       // 16
    int ld = N * NORB;             // 1664

    size_t full = (size_t)K * ld * ld * 2;             // floats if complex
    int es = ((size_t)out_size >= full) ? 2 : 1;

    // phase 1: zero exactly the bytes we use, via the rocclr fill path
    // (measured at 6.6 TB/s every iteration on this same buffer).
    size_t nbytes = (size_t)K * ld * ld * (es == 2 ? 8 : 4);
    hipMemsetAsync(d_out, 0, nbytes, stream);

    // phase 2: scatter nonzero 13x13 blocks (stream-ordered after zeros)
    int nwg = N * K;               // 2048 WGs
    k_sparse<<<nwg, NTHR, 0, stream>>>(hopping, onsite, kpoints, cell_shift,
                                       edge_index, out, N, E, K, ld, es);
}